// Round 2
// baseline (2187.143 us; speedup 1.0000x reference)
//
#include <hip/hip_runtime.h>
#include <hip/hip_bf16.h>

#define BS_   2048
#define HID_  512
#define PH_   32

typedef _Float16 half8 __attribute__((ext_vector_type(8)));
typedef float floatx4 __attribute__((ext_vector_type(4)));

__device__ __forceinline__ float sigf(float x) { return 1.f / (1.f + __expf(-x)); }
__device__ __forceinline__ float tanhfast(float x) {
    float e = __expf(2.f * x);          // e=inf -> 1, e->0 -> -1 : safe at extremes
    return 1.f - 2.f / (e + 1.f);
}

// ---------------------------------------------------------------------------
// Prep: fp32 -> fp16 weights, combined weight W_ih+W_hh, combined bias, z16,
// and zero the inter-block step counters.
// ---------------------------------------------------------------------------
__global__ __launch_bounds__(256) void prep_kernel(
    const float* __restrict__ Wih, const float* __restrict__ Whh,
    const float* __restrict__ bih, const float* __restrict__ bhh,
    const float* __restrict__ z,
    _Float16* __restrict__ wih16, _Float16* __restrict__ wsum16,
    _Float16* __restrict__ z16, float* __restrict__ bsum,
    int* __restrict__ cnt)
{
    int i = blockIdx.x * 256 + threadIdx.x;          // [0, 1048576)
    if (i < BS_ * HID_) z16[i] = (_Float16)z[i];
    if (i < 4 * HID_ * HID_) {
        float a = Wih[i];
        wih16[i]  = (_Float16)a;
        wsum16[i] = (_Float16)(a + Whh[i]);
    }
    if (i < 4 * HID_) bsum[i] = bih[i] + bhh[i];
    if (i < 256) cnt[i] = 0;
}

// ---------------------------------------------------------------------------
// Persistent LSTM: one cooperative kernel runs all 32 steps.
// Grid = 256 blocks x 512 threads (8 waves -> 2 waves/SIMD).
//   blockIdx = ib*32 + j : ib in [0,8) = 256-row batch tile, j in [0,32) =
//   16 hidden units -> 64 gate rows (i,f,g,o x 16).
// Weight slice (64 rows x 512 K fp16 = 64 KB) staged into LDS ONCE
// (wih16 for t=0, restaged to wsum16 after), XOR-swizzled on 16B blocks.
// Cell state c lives in VGPRs across all 32 steps. Cross-step dependency is
// only within an ib-group (its 32 j-blocks produce all 512 columns of
// h[t][ib rows]) -> per-(ib,t) counters: produce = threadfence + atomicAdd,
// consume = agent-scope acquire spin. Cooperative launch guarantees residency.
// ---------------------------------------------------------------------------
__device__ __forceinline__ void stage_weights(_Float16* Wl, const _Float16* Wg,
                                              int j, int tid)
{
#pragma unroll
    for (int rep = 0; rep < 8; ++rep) {
        int idx = rep * 512 + tid;      // [0, 4096) over (row n, 16B-block kb)
        int n  = idx >> 6;
        int kb = idx & 63;
        int g  = n >> 4, u = n & 15;
        const half8* src = (const half8*)(Wg + ((size_t)(g * HID_ + j * 16 + u)) * HID_ + kb * 8);
        int phys = (kb & 56) | ((kb & 7) ^ (n & 7));
        *(half8*)((char*)Wl + n * 1024 + phys * 16) = *src;
    }
}

__global__ __launch_bounds__(512, 2) void lstm_persist(
    const _Float16* __restrict__ wih16, const _Float16* __restrict__ wsum16,
    const float* __restrict__ bsum, const _Float16* __restrict__ z16,
    _Float16* __restrict__ hs, int* __restrict__ cnt)
{
    __shared__ _Float16 Wl[64 * 512];   // 64 KB

    const int tid  = threadIdx.x;
    const int j    = blockIdx.x & 31;
    const int ib   = blockIdx.x >> 5;
    const int lane = tid & 63;
    const int wv   = tid >> 6;          // wave 0..7 -> M strip of 32 rows
    const int qw   = lane >> 4;         // quad 0..3
    const int ln   = lane & 15;
    const int hid  = j * 16 + ln;

    stage_weights(Wl, wih16, j, tid);

    float bias[4];
#pragma unroll
    for (int g = 0; g < 4; ++g) bias[g] = bsum[g * HID_ + hid];

    float c[2][4];
#pragma unroll
    for (int mt = 0; mt < 2; ++mt)
#pragma unroll
        for (int r = 0; r < 4; ++r) c[mt][r] = 0.f;

    const char* Bl = (const char*)Wl;
    const int tE = (qw ^ (ln & 7)) * 16;    // swizzled byte offset, kk-even

    __syncthreads();

    for (int t = 0; t < PH_; ++t) {
        const _Float16* x = (t == 0) ? z16 : hs + (size_t)(t - 1) * BS_ * HID_;

        if (t >= 1) {
            if (tid == 0) {
                while (__hip_atomic_load(&cnt[ib * 32 + t - 1], __ATOMIC_ACQUIRE,
                                         __HIP_MEMORY_SCOPE_AGENT) < 32) {
                    __builtin_amdgcn_s_sleep(1);
                }
            }
            __syncthreads();
        }

        floatx4 acc[2][4];
#pragma unroll
        for (int mt = 0; mt < 2; ++mt)
#pragma unroll
            for (int g = 0; g < 4; ++g) acc[mt][g] = (floatx4){0.f, 0.f, 0.f, 0.f};

        // A fragment: A[m = ln][k = qw*8 + jj], straight from global (L2-hot)
        const _Float16* A0 = x + (size_t)(ib * 256 + wv * 32 + ln) * HID_ + qw * 8;

#pragma unroll
        for (int kk = 0; kk < 16; ++kk) {
            half8 a0 = *(const half8*)(A0 + kk * 32);
            half8 a1 = *(const half8*)(A0 + 16 * HID_ + kk * 32);
            half8 b[4];
#pragma unroll
            for (int g = 0; g < 4; ++g) {
                int off = (g * 16 + ln) * 1024 + (kk >> 1) * 128 + (tE ^ ((kk & 1) << 6));
                b[g] = *(const half8*)(Bl + off);
            }
#pragma unroll
            for (int g = 0; g < 4; ++g) {
                acc[0][g] = __builtin_amdgcn_mfma_f32_16x16x32_f16(a0, b[g], acc[0][g], 0, 0, 0);
                acc[1][g] = __builtin_amdgcn_mfma_f32_16x16x32_f16(a1, b[g], acc[1][g], 0, 0, 0);
            }
        }

        // epilogue: C/D layout col=ln, row=qw*4+r; all 4 gates in-thread
        _Float16* hb = hs + (size_t)t * BS_ * HID_
                          + (size_t)(ib * 256 + wv * 32 + qw * 4) * HID_ + hid;
#pragma unroll
        for (int mt = 0; mt < 2; ++mt) {
#pragma unroll
            for (int r = 0; r < 4; ++r) {
                float gi = acc[mt][0][r] + bias[0];
                float gf = acc[mt][1][r] + bias[1];
                float gg = acc[mt][2][r] + bias[2];
                float go = acc[mt][3][r] + bias[3];
                float cn = sigf(gf) * c[mt][r] + sigf(gi) * tanhfast(gg);
                float hn = sigf(go) * tanhfast(cn);
                c[mt][r] = cn;
                hb[(size_t)(mt * 16 + r) * HID_] = (_Float16)hn;
            }
        }

        __threadfence();        // release h[t] stores device-wide
        __syncthreads();        // all threads' stores done before the signal
        if (t == 0) {
            if (tid == 0) atomicAdd(&cnt[ib * 32 + 0], 1);
            stage_weights(Wl, wsum16, j, tid);   // switch to W_ih+W_hh
            __syncthreads();
        } else if (t < PH_ - 1) {
            if (tid == 0) atomicAdd(&cnt[ib * 32 + t], 1);
        }
    }
}

// ---------------------------------------------------------------------------
// y[b,t,:] = hs[t][b,:] @ W_d^T + b_d. One wave per (b,t) row.
// ---------------------------------------------------------------------------
__global__ __launch_bounds__(256) void dense_kernel(
    const _Float16* __restrict__ hs, const float* __restrict__ Wd,
    const float* __restrict__ bd, float* __restrict__ y)
{
    int gw   = (blockIdx.x * 256 + threadIdx.x) >> 6;   // wave id [0, 65536)
    int lane = threadIdx.x & 63;
    int tt = gw & 31, b = gw >> 5;
    half8 h = *(const half8*)(hs + ((size_t)tt * BS_ + b) * HID_ + lane * 8);
    float s0 = 0.f, s1 = 0.f;
#pragma unroll
    for (int k = 0; k < 8; ++k) {
        float hv = (float)h[k];
        s0 += hv * Wd[lane * 8 + k];
        s1 += hv * Wd[HID_ + lane * 8 + k];
    }
#pragma unroll
    for (int m = 32; m >= 1; m >>= 1) {
        s0 += __shfl_xor(s0, m);
        s1 += __shfl_xor(s1, m);
    }
    if (lane == 0) {
        float* o = y + ((size_t)b * PH_ + tt) * 2;
        o[0] = s0 + bd[0];
        o[1] = s1 + bd[1];
    }
}

// ---------------------------------------------------------------------------
extern "C" void kernel_launch(void* const* d_in, const int* in_sizes, int n_in,
                              void* d_out, int out_size, void* d_ws, size_t ws_size,
                              hipStream_t stream)
{
    (void)in_sizes; (void)n_in; (void)out_size; (void)ws_size;
    // setup_inputs order: hist(0, unused), z(1), W_ih(2), W_hh(3), b_ih(4),
    //                     b_hh(5), W_d(6), b_d(7)
    const float* z   = (const float*)d_in[1];
    const float* Wih = (const float*)d_in[2];
    const float* Whh = (const float*)d_in[3];
    const float* bih = (const float*)d_in[4];
    const float* bhh = (const float*)d_in[5];
    const float* Wd  = (const float*)d_in[6];
    const float* bd  = (const float*)d_in[7];
    float* y = (float*)d_out;

    char* ws = (char*)d_ws;
    _Float16* hs     = (_Float16*)ws;                          // 32*2048*512*2 = 64 MB
    _Float16* z16    = (_Float16*)(ws + (size_t)67108864);     // 2 MB
    _Float16* wih16  = (_Float16*)(ws + (size_t)69206016);     // 2 MB
    _Float16* wsum16 = (_Float16*)(ws + (size_t)71303168);     // 2 MB
    float*    bsum   = (float*)   (ws + (size_t)73400320);     // 8 KB
    int*      cnt    = (int*)     (ws + (size_t)73408512);     // 1 KB

    prep_kernel<<<4096, 256, 0, stream>>>(Wih, Whh, bih, bhh, z,
                                          wih16, wsum16, z16, bsum, cnt);

    {
        const void* k = (const void*)lstm_persist;
        void* args[] = {(void*)&wih16, (void*)&wsum16, (void*)&bsum,
                        (void*)&z16, (void*)&hs, (void*)&cnt};
        hipLaunchCooperativeKernel(k, dim3(256), dim3(512), args, 0, stream);
    }

    dense_kernel<<<16384, 256, 0, stream>>>(hs, Wd, bd, y);
}

// Round 3
// 694.389 us; speedup vs baseline: 3.1497x; 3.1497x over previous
//
#include <hip/hip_runtime.h>
#include <hip/hip_bf16.h>

#define BS_   2048
#define HID_  512
#define PH_   32

typedef _Float16 half8 __attribute__((ext_vector_type(8)));
typedef float floatx4 __attribute__((ext_vector_type(4)));

__device__ __forceinline__ float sigf(float x) { return 1.f / (1.f + __expf(-x)); }
__device__ __forceinline__ float tanhfast(float x) {
    float e = __expf(2.f * x);          // e=inf -> 1, e->0 -> -1 : safe at extremes
    return 1.f - 2.f / (e + 1.f);
}

// ---------------------------------------------------------------------------
// Prep: fp32 -> fp16 weights, combined weight W_ih+W_hh, combined bias, z16,
// and zero the inter-block step counters.
// ---------------------------------------------------------------------------
__global__ __launch_bounds__(256) void prep_kernel(
    const float* __restrict__ Wih, const float* __restrict__ Whh,
    const float* __restrict__ bih, const float* __restrict__ bhh,
    const float* __restrict__ z,
    _Float16* __restrict__ wih16, _Float16* __restrict__ wsum16,
    _Float16* __restrict__ z16, float* __restrict__ bsum,
    int* __restrict__ cnt)
{
    int i = blockIdx.x * 256 + threadIdx.x;          // [0, 1048576)
    if (i < BS_ * HID_) z16[i] = (_Float16)z[i];
    if (i < 4 * HID_ * HID_) {
        float a = Wih[i];
        wih16[i]  = (_Float16)a;
        wsum16[i] = (_Float16)(a + Whh[i]);
    }
    if (i < 4 * HID_) bsum[i] = bih[i] + bhh[i];
    if (i < 256) cnt[i] = 0;
}

// ---------------------------------------------------------------------------
// Persistent LSTM, one cooperative kernel for all 32 steps.
// Grid = 256 blocks x 512 threads.
//   ib = blockIdx & 7  : 256-row batch tile  (all 32 blocks of a group land on
//                        one XCD under round-robin dispatch -- heuristic only)
//   j  = blockIdx >> 3 : 16 hidden units -> 64 gate rows (i,f,g,o x 16)
// Weights staged in LDS once (wih16 for t=0, then wsum16); c in VGPRs.
// Sync protocol (device-scope, placement-independent):
//   producer: __syncthreads (drains each wave's stores to L2) ->
//             tid0 __threadfence (L2 writeback cache-op covers all writers) ->
//             tid0 atomicAdd(flag)
//   consumer: tid0 spins on atomic fetch_add(flag, 0) -- RMW executes at the
//             coherence point, CANNOT be served by a stale cached line (the
//             R2 failure mode: acquire-load hit stale L2, visibility was
//             eviction-driven ~63us/step) -> acquire fence -> __syncthreads
// ---------------------------------------------------------------------------
__device__ __forceinline__ void stage_weights(_Float16* Wl, const _Float16* Wg,
                                              int j, int tid)
{
#pragma unroll
    for (int rep = 0; rep < 8; ++rep) {
        int idx = rep * 512 + tid;      // [0, 4096) over (row n, 16B-block kb)
        int n  = idx >> 6;
        int kb = idx & 63;
        int g  = n >> 4, u = n & 15;
        const half8* src = (const half8*)(Wg + ((size_t)(g * HID_ + j * 16 + u)) * HID_ + kb * 8);
        int phys = (kb & 56) | ((kb & 7) ^ (n & 7));
        *(half8*)((char*)Wl + n * 1024 + phys * 16) = *src;
    }
}

__global__ __launch_bounds__(512, 2) void lstm_persist(
    const _Float16* __restrict__ wih16, const _Float16* __restrict__ wsum16,
    const float* __restrict__ bsum, const _Float16* __restrict__ z16,
    _Float16* __restrict__ hs, int* __restrict__ cnt)
{
    __shared__ _Float16 Wl[64 * 512];   // 64 KB

    const int tid  = threadIdx.x;
    const int ib   = blockIdx.x & 7;    // XCD co-location for the sync group
    const int j    = blockIdx.x >> 3;
    const int lane = tid & 63;
    const int wv   = tid >> 6;          // wave 0..7 -> M strip of 32 rows
    const int qw   = lane >> 4;         // quad 0..3
    const int ln   = lane & 15;
    const int hid  = j * 16 + ln;

    stage_weights(Wl, wih16, j, tid);

    float bias[4];
#pragma unroll
    for (int g = 0; g < 4; ++g) bias[g] = bsum[g * HID_ + hid];

    float c[2][4];
#pragma unroll
    for (int mt = 0; mt < 2; ++mt)
#pragma unroll
        for (int r = 0; r < 4; ++r) c[mt][r] = 0.f;

    const char* Bl = (const char*)Wl;
    const int tE = (qw ^ (ln & 7)) * 16;    // swizzled byte offset, kk-even

    __syncthreads();

    for (int t = 0; t < PH_; ++t) {
        const _Float16* x = (t == 0) ? z16 : hs + (size_t)(t - 1) * BS_ * HID_;

        if (t >= 1) {
            if (tid == 0) {
                while (__hip_atomic_fetch_add(&cnt[ib * 32 + t - 1], 0,
                                              __ATOMIC_RELAXED,
                                              __HIP_MEMORY_SCOPE_AGENT) < 32) {
                    __builtin_amdgcn_s_sleep(2);
                }
                __builtin_amdgcn_fence(__ATOMIC_ACQUIRE, "agent");
            }
            __syncthreads();
        }

        floatx4 acc[2][4];
#pragma unroll
        for (int mt = 0; mt < 2; ++mt)
#pragma unroll
            for (int g = 0; g < 4; ++g) acc[mt][g] = (floatx4){0.f, 0.f, 0.f, 0.f};

        // A fragment: A[m = ln][k = qw*8 + jj], straight from global (L2-hot)
        const _Float16* A0 = x + (size_t)(ib * 256 + wv * 32 + ln) * HID_ + qw * 8;

#pragma unroll
        for (int kk = 0; kk < 16; ++kk) {
            half8 a0 = *(const half8*)(A0 + kk * 32);
            half8 a1 = *(const half8*)(A0 + 16 * HID_ + kk * 32);
            half8 b[4];
#pragma unroll
            for (int g = 0; g < 4; ++g) {
                int off = (g * 16 + ln) * 1024 + (kk >> 1) * 128 + (tE ^ ((kk & 1) << 6));
                b[g] = *(const half8*)(Bl + off);
            }
#pragma unroll
            for (int g = 0; g < 4; ++g) {
                acc[0][g] = __builtin_amdgcn_mfma_f32_16x16x32_f16(a0, b[g], acc[0][g], 0, 0, 0);
                acc[1][g] = __builtin_amdgcn_mfma_f32_16x16x32_f16(a1, b[g], acc[1][g], 0, 0, 0);
            }
        }

        // epilogue: C/D layout col=ln, row=qw*4+r; all 4 gates in-thread
        _Float16* hb = hs + (size_t)t * BS_ * HID_
                          + (size_t)(ib * 256 + wv * 32 + qw * 4) * HID_ + hid;
#pragma unroll
        for (int mt = 0; mt < 2; ++mt) {
#pragma unroll
            for (int r = 0; r < 4; ++r) {
                float gi = acc[mt][0][r] + bias[0];
                float gf = acc[mt][1][r] + bias[1];
                float gg = acc[mt][2][r] + bias[2];
                float go = acc[mt][3][r] + bias[3];
                float cn = sigf(gf) * c[mt][r] + sigf(gi) * tanhfast(gg);
                float hn = sigf(go) * tanhfast(cn);
                c[mt][r] = cn;
                hb[(size_t)(mt * 16 + r) * HID_] = (_Float16)hn;
            }
        }

        // all waves drain their stores to L2 at this barrier (compiler emits
        // s_waitcnt vmcnt(0) before s_barrier), then ONE thread does the L2
        // writeback cache-op + signal.
        __syncthreads();
        if (t == 0) {
            if (tid == 0) { __threadfence(); atomicAdd(&cnt[ib * 32 + 0], 1); }
            stage_weights(Wl, wsum16, j, tid);   // switch to W_ih+W_hh
            __syncthreads();
        } else if (t < PH_ - 1) {
            if (tid == 0) { __threadfence(); atomicAdd(&cnt[ib * 32 + t], 1); }
        }
    }
}

// ---------------------------------------------------------------------------
// y[b,t,:] = hs[t][b,:] @ W_d^T + b_d. One wave per (b,t) row.
// ---------------------------------------------------------------------------
__global__ __launch_bounds__(256) void dense_kernel(
    const _Float16* __restrict__ hs, const float* __restrict__ Wd,
    const float* __restrict__ bd, float* __restrict__ y)
{
    int gw   = (blockIdx.x * 256 + threadIdx.x) >> 6;   // wave id [0, 65536)
    int lane = threadIdx.x & 63;
    int tt = gw & 31, b = gw >> 5;
    half8 h = *(const half8*)(hs + ((size_t)tt * BS_ + b) * HID_ + lane * 8);
    float s0 = 0.f, s1 = 0.f;
#pragma unroll
    for (int k = 0; k < 8; ++k) {
        float hv = (float)h[k];
        s0 += hv * Wd[lane * 8 + k];
        s1 += hv * Wd[HID_ + lane * 8 + k];
    }
#pragma unroll
    for (int m = 32; m >= 1; m >>= 1) {
        s0 += __shfl_xor(s0, m);
        s1 += __shfl_xor(s1, m);
    }
    if (lane == 0) {
        float* o = y + ((size_t)b * PH_ + tt) * 2;
        o[0] = s0 + bd[0];
        o[1] = s1 + bd[1];
    }
}

// ---------------------------------------------------------------------------
extern "C" void kernel_launch(void* const* d_in, const int* in_sizes, int n_in,
                              void* d_out, int out_size, void* d_ws, size_t ws_size,
                              hipStream_t stream)
{
    (void)in_sizes; (void)n_in; (void)out_size; (void)ws_size;
    // setup_inputs order: hist(0, unused), z(1), W_ih(2), W_hh(3), b_ih(4),
    //                     b_hh(5), W_d(6), b_d(7)
    const float* z   = (const float*)d_in[1];
    const float* Wih = (const float*)d_in[2];
    const float* Whh = (const float*)d_in[3];
    const float* bih = (const float*)d_in[4];
    const float* bhh = (const float*)d_in[5];
    const float* Wd  = (const float*)d_in[6];
    const float* bd  = (const float*)d_in[7];
    float* y = (float*)d_out;

    char* ws = (char*)d_ws;
    _Float16* hs     = (_Float16*)ws;                          // 32*2048*512*2 = 64 MB
    _Float16* z16    = (_Float16*)(ws + (size_t)67108864);     // 2 MB
    _Float16* wih16  = (_Float16*)(ws + (size_t)69206016);     // 2 MB
    _Float16* wsum16 = (_Float16*)(ws + (size_t)71303168);     // 2 MB
    float*    bsum   = (float*)   (ws + (size_t)73400320);     // 8 KB
    int*      cnt    = (int*)     (ws + (size_t)73408512);     // 1 KB

    prep_kernel<<<4096, 256, 0, stream>>>(Wih, Whh, bih, bhh, z,
                                          wih16, wsum16, z16, bsum, cnt);

    {
        const void* k = (const void*)lstm_persist;
        void* args[] = {(void*)&wih16, (void*)&wsum16, (void*)&bsum,
                        (void*)&z16, (void*)&hs, (void*)&cnt};
        hipLaunchCooperativeKernel(k, dim3(256), dim3(512), args, 0, stream);
    }

    dense_kernel<<<16384, 256, 0, stream>>>(hs, Wd, bd, y);
}

// Round 4
// 474.088 us; speedup vs baseline: 4.6134x; 1.4647x over previous
//
#include <hip/hip_runtime.h>
#include <hip/hip_bf16.h>

#define BS_   2048
#define HID_  512
#define PH_   32

// s_getreg: size=4 bits (sz-1=3), offset=0, id=20 (HW_REG_XCC_ID, m09-verified)
#define HWREG_XCC_ID ((3 << 11) | (0 << 6) | 20)

typedef _Float16 half8 __attribute__((ext_vector_type(8)));
typedef float floatx4 __attribute__((ext_vector_type(4)));

__device__ __forceinline__ float sigf(float x) { return 1.f / (1.f + __expf(-x)); }
__device__ __forceinline__ float tanhfast(float x) {
    float e = __expf(2.f * x);          // e=inf -> 1, e->0 -> -1 : safe at extremes
    return 1.f - 2.f / (e + 1.f);
}

// ---------------------------------------------------------------------------
// Prep: fp32 -> fp16 weights, combined weight W_ih+W_hh, combined bias, z16,
// and zero the step counters (cnt[0..255]) + per-group XCD masks (cnt[256..263]).
// ---------------------------------------------------------------------------
__global__ __launch_bounds__(256) void prep_kernel(
    const float* __restrict__ Wih, const float* __restrict__ Whh,
    const float* __restrict__ bih, const float* __restrict__ bhh,
    const float* __restrict__ z,
    _Float16* __restrict__ wih16, _Float16* __restrict__ wsum16,
    _Float16* __restrict__ z16, float* __restrict__ bsum,
    int* __restrict__ cnt)
{
    int i = blockIdx.x * 256 + threadIdx.x;          // [0, 1048576)
    if (i < BS_ * HID_) z16[i] = (_Float16)z[i];
    if (i < 4 * HID_ * HID_) {
        float a = Wih[i];
        wih16[i]  = (_Float16)a;
        wsum16[i] = (_Float16)(a + Whh[i]);
    }
    if (i < 4 * HID_) bsum[i] = bih[i] + bhh[i];
    if (i < 264) cnt[i] = 0;
}

// ---------------------------------------------------------------------------
// Persistent LSTM, one cooperative kernel for all 32 steps.
// Grid = 256 blocks x 512 threads.
//   ib = blockIdx & 7  : 256-row batch tile (round-robin dispatch -> the 32
//                        blocks of a group share one XCD / one L2)
//   j  = blockIdx >> 3 : 16 hidden units -> 64 gate rows (i,f,g,o x 16)
// Sync protocol, runtime-verified two-tier:
//   t=0 signal + t=1 wait: FENCED (threadfence release / agent acquire) --
//     correct on any placement; also publishes+reads the group XCD mask.
//   t>=1 signals, t>=2 waits: if popcount(mask)==1 (all members on one L2):
//     fence-free -- __syncthreads drains stores to the shared L2 (vmcnt ack),
//     relaxed coherence-point RMW carries the flag, no wbl2/inv cache-ops.
//     Else: keep the fenced protocol (R3 semantics).
//   Failure mode of a wrong placement guess is the slow path, never bad data.
// ---------------------------------------------------------------------------
__device__ __forceinline__ void stage_weights(_Float16* Wl, const _Float16* Wg,
                                              int j, int tid)
{
#pragma unroll
    for (int rep = 0; rep < 8; ++rep) {
        int idx = rep * 512 + tid;      // [0, 4096) over (row n, 16B-block kb)
        int n  = idx >> 6;
        int kb = idx & 63;
        int g  = n >> 4, u = n & 15;
        const half8* src = (const half8*)(Wg + ((size_t)(g * HID_ + j * 16 + u)) * HID_ + kb * 8);
        int phys = (kb & 56) | ((kb & 7) ^ (n & 7));
        *(half8*)((char*)Wl + n * 1024 + phys * 16) = *src;
    }
}

__global__ __launch_bounds__(512, 2) void lstm_persist(
    const _Float16* __restrict__ wih16, const _Float16* __restrict__ wsum16,
    const float* __restrict__ bsum, const _Float16* __restrict__ z16,
    _Float16* __restrict__ hs, int* __restrict__ cnt)
{
    __shared__ _Float16 Wl[64 * 512];   // 64 KB

    const int tid  = threadIdx.x;
    const int ib   = blockIdx.x & 7;    // XCD co-location for the sync group
    const int j    = blockIdx.x >> 3;
    const int lane = tid & 63;
    const int wv   = tid >> 6;          // wave 0..7 -> M strip of 32 rows
    const int qw   = lane >> 4;         // quad 0..3
    const int ln   = lane & 15;
    const int hid  = j * 16 + ln;

    stage_weights(Wl, wih16, j, tid);

    float bias[4];
#pragma unroll
    for (int g = 0; g < 4; ++g) bias[g] = bsum[g * HID_ + hid];

    float c[2][4];
#pragma unroll
    for (int mt = 0; mt < 2; ++mt)
#pragma unroll
        for (int r = 0; r < 4; ++r) c[mt][r] = 0.f;

    const char* Bl = (const char*)Wl;
    const int tE = (qw ^ (ln & 7)) * 16;    // swizzled byte offset, kk-even

    bool fast = false;                  // valid in tid0 only

    __syncthreads();

    for (int t = 0; t < PH_; ++t) {
        const _Float16* x = (t == 0) ? z16 : hs + (size_t)(t - 1) * BS_ * HID_;

        if (t >= 1) {
            if (tid == 0) {
                while (__hip_atomic_fetch_add(&cnt[ib * 32 + t - 1], 0,
                                              __ATOMIC_RELAXED,
                                              __HIP_MEMORY_SCOPE_AGENT) < 32) {
                    __builtin_amdgcn_s_sleep(1);
                }
                if (t == 1) {
                    __builtin_amdgcn_fence(__ATOMIC_ACQUIRE, "agent");
                    int m = __hip_atomic_fetch_add(&cnt[256 + ib], 0,
                                                   __ATOMIC_RELAXED,
                                                   __HIP_MEMORY_SCOPE_AGENT);
                    fast = (__popc((unsigned)m) == 1);
                } else if (fast) {
                    __builtin_amdgcn_fence(__ATOMIC_ACQUIRE, "workgroup");
                } else {
                    __builtin_amdgcn_fence(__ATOMIC_ACQUIRE, "agent");
                }
            }
            __syncthreads();
        }

        floatx4 acc[2][4];
#pragma unroll
        for (int mt = 0; mt < 2; ++mt)
#pragma unroll
            for (int g = 0; g < 4; ++g) acc[mt][g] = (floatx4){0.f, 0.f, 0.f, 0.f};

        // A fragment: A[m = ln][k = qw*8 + jj], straight from global (L2-hot)
        const _Float16* A0 = x + (size_t)(ib * 256 + wv * 32 + ln) * HID_ + qw * 8;

#pragma unroll
        for (int kk = 0; kk < 16; ++kk) {
            half8 a0 = *(const half8*)(A0 + kk * 32);
            half8 a1 = *(const half8*)(A0 + 16 * HID_ + kk * 32);
            half8 b[4];
#pragma unroll
            for (int g = 0; g < 4; ++g) {
                int off = (g * 16 + ln) * 1024 + (kk >> 1) * 128 + (tE ^ ((kk & 1) << 6));
                b[g] = *(const half8*)(Bl + off);
            }
#pragma unroll
            for (int g = 0; g < 4; ++g) {
                acc[0][g] = __builtin_amdgcn_mfma_f32_16x16x32_f16(a0, b[g], acc[0][g], 0, 0, 0);
                acc[1][g] = __builtin_amdgcn_mfma_f32_16x16x32_f16(a1, b[g], acc[1][g], 0, 0, 0);
            }
        }

        // epilogue: C/D layout col=ln, row=qw*4+r; all 4 gates in-thread
        _Float16* hb = hs + (size_t)t * BS_ * HID_
                          + (size_t)(ib * 256 + wv * 32 + qw * 4) * HID_ + hid;
#pragma unroll
        for (int mt = 0; mt < 2; ++mt) {
#pragma unroll
            for (int r = 0; r < 4; ++r) {
                float gi = acc[mt][0][r] + bias[0];
                float gf = acc[mt][1][r] + bias[1];
                float gg = acc[mt][2][r] + bias[2];
                float go = acc[mt][3][r] + bias[3];
                float cn = sigf(gf) * c[mt][r] + sigf(gi) * tanhfast(gg);
                float hn = sigf(go) * tanhfast(cn);
                c[mt][r] = cn;
                hb[(size_t)(mt * 16 + r) * HID_] = (_Float16)hn;
            }
        }

        // Barrier drains every wave's h-stores (s_waitcnt vmcnt(0) precedes
        // s_barrier) -> stores are acked by the XCD L2. Then ONE thread signals.
        __syncthreads();
        if (t == 0) {
            if (tid == 0) {
                int xcd = __builtin_amdgcn_s_getreg(HWREG_XCC_ID) & 0xf;
                __hip_atomic_fetch_or(&cnt[256 + ib], 1 << xcd,
                                      __ATOMIC_RELAXED, __HIP_MEMORY_SCOPE_AGENT);
                __threadfence();            // release: h[0] + mask before signal
                atomicAdd(&cnt[ib * 32 + 0], 1);
            }
            stage_weights(Wl, wsum16, j, tid);   // switch to W_ih+W_hh
            __syncthreads();
        } else if (t < PH_ - 1) {
            if (tid == 0) {
                if (fast) {
                    __hip_atomic_fetch_add(&cnt[ib * 32 + t], 1,
                                           __ATOMIC_RELAXED,
                                           __HIP_MEMORY_SCOPE_AGENT);
                } else {
                    __threadfence();
                    atomicAdd(&cnt[ib * 32 + t], 1);
                }
            }
        }
    }
}

// ---------------------------------------------------------------------------
// y[b,t,:] = hs[t][b,:] @ W_d^T + b_d. One wave per (b,t) row.
// ---------------------------------------------------------------------------
__global__ __launch_bounds__(256) void dense_kernel(
    const _Float16* __restrict__ hs, const float* __restrict__ Wd,
    const float* __restrict__ bd, float* __restrict__ y)
{
    int gw   = (blockIdx.x * 256 + threadIdx.x) >> 6;   // wave id [0, 65536)
    int lane = threadIdx.x & 63;
    int tt = gw & 31, b = gw >> 5;
    half8 h = *(const half8*)(hs + ((size_t)tt * BS_ + b) * HID_ + lane * 8);
    float s0 = 0.f, s1 = 0.f;
#pragma unroll
    for (int k = 0; k < 8; ++k) {
        float hv = (float)h[k];
        s0 += hv * Wd[lane * 8 + k];
        s1 += hv * Wd[HID_ + lane * 8 + k];
    }
#pragma unroll
    for (int m = 32; m >= 1; m >>= 1) {
        s0 += __shfl_xor(s0, m);
        s1 += __shfl_xor(s1, m);
    }
    if (lane == 0) {
        float* o = y + ((size_t)b * PH_ + tt) * 2;
        o[0] = s0 + bd[0];
        o[1] = s1 + bd[1];
    }
}

// ---------------------------------------------------------------------------
extern "C" void kernel_launch(void* const* d_in, const int* in_sizes, int n_in,
                              void* d_out, int out_size, void* d_ws, size_t ws_size,
                              hipStream_t stream)
{
    (void)in_sizes; (void)n_in; (void)out_size; (void)ws_size;
    // setup_inputs order: hist(0, unused), z(1), W_ih(2), W_hh(3), b_ih(4),
    //                     b_hh(5), W_d(6), b_d(7)
    const float* z   = (const float*)d_in[1];
    const float* Wih = (const float*)d_in[2];
    const float* Whh = (const float*)d_in[3];
    const float* bih = (const float*)d_in[4];
    const float* bhh = (const float*)d_in[5];
    const float* Wd  = (const float*)d_in[6];
    const float* bd  = (const float*)d_in[7];
    float* y = (float*)d_out;

    char* ws = (char*)d_ws;
    _Float16* hs     = (_Float16*)ws;                          // 32*2048*512*2 = 64 MB
    _Float16* z16    = (_Float16*)(ws + (size_t)67108864);     // 2 MB
    _Float16* wih16  = (_Float16*)(ws + (size_t)69206016);     // 2 MB
    _Float16* wsum16 = (_Float16*)(ws + (size_t)71303168);     // 2 MB
    float*    bsum   = (float*)   (ws + (size_t)73400320);     // 8 KB
    int*      cnt    = (int*)     (ws + (size_t)73408512);     // 264 ints

    prep_kernel<<<4096, 256, 0, stream>>>(Wih, Whh, bih, bhh, z,
                                          wih16, wsum16, z16, bsum, cnt);

    {
        const void* k = (const void*)lstm_persist;
        void* args[] = {(void*)&wih16, (void*)&wsum16, (void*)&bsum,
                        (void*)&z16, (void*)&hs, (void*)&cnt};
        hipLaunchCooperativeKernel(k, dim3(256), dim3(512), args, 0, stream);
    }

    dense_kernel<<<16384, 256, 0, stream>>>(hs, Wd, bd, y);
}